// Round 5
// baseline (1292.716 us; speedup 1.0000x reference)
//
#include <hip/hip_runtime.h>

typedef _Float16 half8_t __attribute__((ext_vector_type(8)));
typedef float    f32x4   __attribute__((ext_vector_type(4)));

#define T_STEPS 1024
#define BATCH   128
#define HID     128
#define GATES   512
#define STACK   1024

__device__ __forceinline__ float sigf(float x)     { return 1.0f / (1.0f + __expf(-x)); }
__device__ __forceinline__ float tanhfast(float x) { return 1.0f - 2.0f / (1.0f + __expf(2.0f * x)); }
__device__ __forceinline__ unsigned ldu(const unsigned* p) {
    return __hip_atomic_load(p, __ATOMIC_RELAXED, __HIP_MEMORY_SCOPE_AGENT);
}
__device__ __forceinline__ void stu(unsigned* p, unsigned v) {
    __hip_atomic_store(p, v, __ATOMIC_RELAXED, __HIP_MEMORY_SCOPE_AGENT);
}

// grid = 256: blocks [0,128) = layer 0 of row r, [128,256) = layer 1 of row r.
// Round-4 structure (split h/x pipelining, gate-interleaved A-rows, lane-local
// epilogue, tagged u32 ring, lgkm-only barrier, lead-builder) + round-5 change:
// ISSUE-ORDER FIX. Waves issue in order, so with x-part before the epilogue the
// matrix pipe drains and then idles through epilogue+staging+barrier+ds_read
// (~1400 cyc/step of pipe-dead time at 42.7% MfmaUtil). Moving the x-part(t+1)
// MFMA cluster to the END of the step (pinned by sched_barrier(0)) lets those
// 16 MFMAs/wave drain across the barrier window into the next step's ds_read
// latency. s_setprio(1) wraps the critical h-part+epilogue. Accumulation order
// per gate row is unchanged (kc 0..3 then 4..7) -> bitwise-identical output.
__launch_bounds__(512, 2)
__global__ void stack_lstm_pipe3(const float* __restrict__ inputs,
                                 const int*   __restrict__ ops,
                                 const float* __restrict__ w_ih,
                                 const float* __restrict__ w_hh,
                                 const float* __restrict__ b_ih,
                                 const float* __restrict__ b_hh,
                                 float* __restrict__ out,
                                 unsigned* __restrict__ ring,  // [D][BATCH][HID]
                                 unsigned* __restrict__ consw, // [BATCH] watermark
                                 int D)                        // ring depth, pow2 >= 4
{
    const int bx    = blockIdx.x;
    const int layer = bx >> 7;      // 0 or 1
    const int r     = bx & 127;     // batch row
    const int tid   = threadIdx.x;  // 0..511
    const int wv    = tid >> 6;     // wave 0..7
    const int ln    = tid & 63;
    const int ml    = ln & 15;
    const int kg    = ln >> 4;
    const int isel  = ml >> 2;
    const int unit  = 16 * wv + 4 * isel + kg;
    const bool uw   = ((ml & 3) == 0);
    const int mask  = D - 1;

    __shared__ __align__(16) _Float16 vbx[2][HID];  // x-input for step parity p
    __shared__ __align__(16) _Float16 vbh[2][HID];  // h written end of step p^1
    __shared__ int ops_s[T_STEPS];

    // ---- weights as MFMA A-fragments, gate-interleaved rows
    half8_t wf[32];  // [i*8 + kc], kc 0..3 = w_ih cols, 4..7 = w_hh cols
#pragma unroll
    for (int i = 0; i < 4; ++i) {
        const int R = 128 * (ml & 3) + 16 * wv + 4 * i + (ml >> 2);
        const float* rowi = w_ih + (size_t)(layer * GATES + R) * HID;
        const float* rowh = w_hh + (size_t)(layer * GATES + R) * HID;
#pragma unroll
        for (int kc = 0; kc < 8; ++kc) {
            const int k0 = 32 * kc + 8 * kg;
            const float* src = (kc < 4) ? (rowi + k0) : (rowh + (k0 - 128));
            half8_t h;
#pragma unroll
            for (int j = 0; j < 8; j += 2) {
                float2 f = *reinterpret_cast<const float2*>(src + j);
                h[j] = (_Float16)f.x; h[j + 1] = (_Float16)f.y;
            }
            wf[i * 8 + kc] = h;
        }
    }
    float Bb[4];
#pragma unroll
    for (int g = 0; g < 4; ++g)
        Bb[g] = b_ih[layer * GATES + 128 * g + unit] + b_hh[layer * GATES + 128 * g + unit];

    ops_s[tid]       = ops[(size_t)tid * BATCH + r];
    ops_s[tid + 512] = ops[(size_t)(tid + 512) * BATCH + r];

    const bool stager = (tid >= 128 && tid < 256);
    const int  su     = tid - 128;

    float c_cur = 0.f, h_top = 0.f;
    int   pos = 0, cons_seen = 0;
    float xs0 = 0.f;  // L0 stagers: holds x(t+2) entering step t

    // ---- lead-builder: L1 starts only once L0 has produced slot lead-1
    if (layer == 1 && tid == 0) {
        int lead = D - 1; if (lead > 8) lead = 8;  // >= 3 (D >= 4)
        const unsigned* p0 = ring + (size_t)((lead - 1) & mask) * BATCH * HID
                                  + (size_t)r * HID;
        while (((ldu(p0) ^ (unsigned)lead) & 0xFFFFu) != 0u)
            __builtin_amdgcn_s_sleep(8);
    }

    // ---- prologue staging: vbx[0]=in(0), vbx[1]=in(1); vbh[0]=0
    if (stager) {
        if (layer == 0) {
            vbx[0][su] = (_Float16)inputs[(size_t)r * HID + su];
            vbx[1][su] = (_Float16)inputs[(size_t)BATCH * HID + (size_t)r * HID + su];
            xs0 = inputs[(size_t)(2 * BATCH) * HID + (size_t)r * HID + su];  // x(2)
        } else {
#pragma unroll
            for (int s = 0; s < 2; ++s) {
                const unsigned* sp = ring + (size_t)s * BATCH * HID + (size_t)r * HID + su;
                const unsigned ex = (unsigned)(s + 1);
                unsigned v;
                do {
                    v = ldu(sp);
                    if (((v ^ ex) & 0xFFFFu) == 0u) break;
                    __builtin_amdgcn_s_sleep(1);
                } while (true);
                vbx[s][su] = __builtin_bit_cast(_Float16, (unsigned short)(v >> 16));
            }
        }
    }
    if (tid < HID) vbh[0][tid] = (_Float16)0.f;
    __syncthreads();

    // ---- A = x-part of step 0 (from vbx[0])
    f32x4 A[4], N[4];
    A[0] = f32x4{0.f, 0.f, 0.f, 0.f}; A[1] = A[0]; A[2] = A[0]; A[3] = A[0];
#pragma unroll
    for (int kc = 0; kc < 4; ++kc) {
        const half8_t xb = *reinterpret_cast<const half8_t*>(&vbx[0][32 * kc + 8 * kg]);
        A[0] = __builtin_amdgcn_mfma_f32_16x16x32_f16(wf[kc],      xb, A[0], 0, 0, 0);
        A[1] = __builtin_amdgcn_mfma_f32_16x16x32_f16(wf[8 + kc],  xb, A[1], 0, 0, 0);
        A[2] = __builtin_amdgcn_mfma_f32_16x16x32_f16(wf[16 + kc], xb, A[2], 0, 0, 0);
        A[3] = __builtin_amdgcn_mfma_f32_16x16x32_f16(wf[24 + kc], xb, A[3], 0, 0, 0);
    }
    __syncthreads();  // protect vbx[0] from step-0 staging until all read it

    auto step = [&](const int tt, const int PP, f32x4* AC, f32x4* AN) {
        // consumer watermark at step top (slot tt's reads ended 2 steps ago)
        if (layer == 1 && tid == 0 && tt > 0)
            stu(consw + r, (unsigned)tt);
        // spec loads for input(tt+2), latency hidden under this whole step
        unsigned sv = 0; float xnl = 0.f;
        const bool sp2 = (tt + 2 < T_STEPS);
        if (stager) {
            if (layer == 0) {
                if (tt + 3 < T_STEPS)
                    xnl = inputs[(size_t)(tt + 3) * BATCH * HID + (size_t)r * HID + su];
            } else if (sp2) {
                sv = ldu(ring + (size_t)((tt + 2) & mask) * BATCH * HID
                              + (size_t)r * HID + su);
            }
        }
        __builtin_amdgcn_s_setprio(1);
        // ---- h-part (recurrent critical path): K-chunks 4..7 into AC
#pragma unroll
        for (int kc = 0; kc < 4; ++kc) {
            const half8_t hb = *reinterpret_cast<const half8_t*>(&vbh[PP][32 * kc + 8 * kg]);
            AC[0] = __builtin_amdgcn_mfma_f32_16x16x32_f16(wf[4 + kc],  hb, AC[0], 0, 0, 0);
            AC[1] = __builtin_amdgcn_mfma_f32_16x16x32_f16(wf[12 + kc], hb, AC[1], 0, 0, 0);
            AC[2] = __builtin_amdgcn_mfma_f32_16x16x32_f16(wf[20 + kc], hb, AC[2], 0, 0, 0);
            AC[3] = __builtin_amdgcn_mfma_f32_16x16x32_f16(wf[28 + kc], hb, AC[3], 0, 0, 0);
        }
        // ---- lane-local epilogue (gv[reg] = gate reg of unit)
        const f32x4 s01 = (isel & 1) ? AC[1] : AC[0];
        const f32x4 s23 = (isel & 1) ? AC[3] : AC[2];
        const f32x4 gv  = (isel & 2) ? s23 : s01;
        const int   op  = ops_s[tt];
        const float cn = sigf(gv[1] + Bb[1]) * c_cur
                       + sigf(gv[0] + Bb[0]) * tanhfast(gv[2] + Bb[2]);
        const float hn = sigf(gv[3] + Bb[3]) * tanhfast(cn);
        const float hs = op ? hn : h_top;
        if (uw) {
            vbh[PP ^ 1][unit] = (_Float16)hs;
            if (layer == 0) {
                const unsigned short hx = __builtin_bit_cast(unsigned short, (_Float16)hn);
                if (D < T_STEPS && tt >= D) {  // ring backpressure (rare)
                    const int need = tt - D;
                    while (cons_seen < need) {
                        cons_seen = (int)ldu(consw + r);
                        if (cons_seen >= need) break;
                        __builtin_amdgcn_s_sleep(1);
                    }
                }
                stu(ring + (size_t)(tt & mask) * BATCH * HID + (size_t)r * HID + unit,
                    ((unsigned)hx << 16) | (unsigned)((tt + 1) & 0xFFFF));
            } else {
                out[(size_t)(pos + 1) * BATCH * HID + (size_t)r * HID + unit] = hn;
            }
        }
        __builtin_amdgcn_s_setprio(0);
        h_top = hs;
        c_cur = op ? cn : c_cur;
        pos += op;
        // ---- stage vbx[PP] := input(tt+2)
        if (stager && sp2) {
            if (layer == 0) {
                vbx[PP][su] = (_Float16)xs0;
                xs0 = xnl;
            } else {
                unsigned v = sv;
                const unsigned ex = (unsigned)((tt + 3) & 0xFFFF);
                while (((v ^ ex) & 0xFFFFu) != 0u) {
                    __builtin_amdgcn_s_sleep(1);
                    v = ldu(ring + (size_t)((tt + 2) & mask) * BATCH * HID
                                 + (size_t)r * HID + su);
                }
                vbx[PP][su] = __builtin_bit_cast(_Float16, (unsigned short)(v >> 16));
            }
        }
        // ---- x-part for step tt+1 into AN, pinned LAST: these 16 MFMAs/wave
        // have no consumer until next step's h-chain, so they drain through the
        // barrier-sync + next step's ds_read window instead of idling the pipe.
        __builtin_amdgcn_sched_barrier(0);
        AN[0] = f32x4{0.f, 0.f, 0.f, 0.f}; AN[1] = AN[0]; AN[2] = AN[0]; AN[3] = AN[0];
#pragma unroll
        for (int kc = 0; kc < 4; ++kc) {
            const half8_t xb = *reinterpret_cast<const half8_t*>(&vbx[PP ^ 1][32 * kc + 8 * kg]);
            AN[0] = __builtin_amdgcn_mfma_f32_16x16x32_f16(wf[kc],      xb, AN[0], 0, 0, 0);
            AN[1] = __builtin_amdgcn_mfma_f32_16x16x32_f16(wf[8 + kc],  xb, AN[1], 0, 0, 0);
            AN[2] = __builtin_amdgcn_mfma_f32_16x16x32_f16(wf[16 + kc], xb, AN[2], 0, 0, 0);
            AN[3] = __builtin_amdgcn_mfma_f32_16x16x32_f16(wf[24 + kc], xb, AN[3], 0, 0, 0);
        }
        // LDS-drain barrier only; global loads/stores stay in flight
        asm volatile("s_waitcnt lgkmcnt(0)\n\ts_barrier" ::: "memory");
    };

    for (int t = 0; t < T_STEPS; t += 2) {
        step(t,     0, A, N);
        step(t + 1, 1, N, A);
    }

    // final pos (float32 — exact for ints <= 1024)
    if (layer == 1 && tid == 0)
        out[(size_t)(STACK + 1) * BATCH * HID + r] = (float)pos;
}

extern "C" void kernel_launch(void* const* d_in, const int* in_sizes, int n_in,
                              void* d_out, int out_size, void* d_ws, size_t ws_size,
                              hipStream_t stream)
{
    (void)in_sizes; (void)n_in;
    const float* inputs = (const float*)d_in[0];
    const int*   ops    = (const int*)d_in[1];
    const float* w_ih   = (const float*)d_in[2];
    const float* w_hh   = (const float*)d_in[3];
    const float* b_ih   = (const float*)d_in[4];
    const float* b_hh   = (const float*)d_in[5];
    float* out = (float*)d_out;

    // ws layout: [0,4096) cons watermark, then tagged u32 ring [D][128][128]
    unsigned* consw = (unsigned*)d_ws;
    unsigned* ring  = (unsigned*)((char*)d_ws + 4096);

    size_t slot_bytes = (size_t)BATCH * HID * sizeof(unsigned);  // 64 KiB
    size_t avail = (ws_size > 4096) ? (ws_size - 4096) / slot_bytes : 4;
    int D = 4;  // protocol needs D >= 4 (lead 3 + publish lag)
    while ((size_t)(D * 2) <= avail && D < T_STEPS) D *= 2;

    hipMemsetAsync(d_ws, 0, 4096, stream);  // zero watermarks
    hipMemsetAsync(d_out, 0, (size_t)out_size * sizeof(float), stream);

    stack_lstm_pipe3<<<dim3(256), dim3(512), 0, stream>>>(
        inputs, ops, w_ih, w_hh, b_ih, b_hh, out, ring, consw, D);
}